// Round 1
// baseline (1114.413 us; speedup 1.0000x reference)
//
#include <hip/hip_runtime.h>
#include <math.h>

#define KNB      16
#define TNB      2
#define LNB      32          // K*T
#define NODE_IN  128
#define EDGE_IN  64
#define TIME_D   128
#define D_MODEL  320
#define N_HEAD   8
#define D_K      64
#define NHD      512         // N_HEAD*D_K
#define HID      128
#define IN2      448         // 2*NODE_IN + TIME_D + EDGE_IN
#define N_DSTN   8192
#define G        4           // nodes per block (weight reuse factor)
#define BLK      512
#define MSTR     328         // padded m row stride (bf16 elems); 656B rows, 16B aligned

// ---- bf16 helpers (storage = unsigned short so unions/shared stay trivial) ----
__device__ __forceinline__ float2 bf2f2(unsigned u) {
  union { unsigned i; float f; } lo, hi;
  lo.i = u << 16;
  hi.i = u & 0xffff0000u;
  return make_float2(lo.f, hi.f);
}
__device__ __forceinline__ unsigned short f2bf(float f) {
  union { float f; unsigned i; } v; v.f = f;
  unsigned x = v.i;
  return (unsigned short)((x + 0x7fffu + ((x >> 16) & 1u)) >> 16); // RTNE
}

struct Post {
  float x[G][D_MODEL];      // 5120 B : x = fc(ctx)+b+q, then layernormed
  float red[2 * BLK];       // 4096 B : LN reduction scratch
};
union MU {
  unsigned short m[LNB][MSTR];  // 20992 B : per-node message matrix (bf16)
  Post post;                    // aliases m; m is dead before Post is used
};

__global__ __launch_bounds__(BLK, 4)
void tgat_fused(const float* __restrict__ nf, const float* __restrict__ ef,
                const float* __restrict__ dtp, const int* __restrict__ nidx,
                const float* __restrict__ freq, const float* __restrict__ ph,
                const float* __restrict__ wq, const float* __restrict__ wk,
                const float* __restrict__ wv, const float* __restrict__ fcw,
                const float* __restrict__ fcb, const float* __restrict__ lng,
                const float* __restrict__ lnb_, const float* __restrict__ nw,
                const float* __restrict__ nbias, float* __restrict__ out)
{
  const int tid = threadIdx.x;
  const int n0  = blockIdx.x * G;

  __shared__ alignas(16) float sQ[G][D_MODEL];                 // 5.0 KB
  __shared__ alignas(16) float sQH[G][NHD];                    // 8.0 KB (qh, later ctx f32 scratch unused after)
  __shared__ alignas(16) unsigned short sB[G][N_HEAD][D_MODEL];// 20 KB (qk -> mbar -> ctx_bf16)
  __shared__ alignas(16) MU u;                                 // 20.5 KB
  __shared__ float sATT[N_HEAD][LNB];                          // 1 KB
  __shared__ float sFP[TIME_D], sPH[TIME_D];                   // 1 KB
  __shared__ int   sNI[KNB];
  __shared__ float sDT[LNB];

  // ---------------- P0: constants + q = [h_dst | 0(64) | cos(phase)] ----------
  if (tid < TIME_D) { sFP[tid] = freq[tid]; sPH[tid] = ph[tid]; }
  __syncthreads();
  for (int idx = tid; idx < G * D_MODEL; idx += BLK) {
    int g = idx / D_MODEL, d = idx - g * D_MODEL;
    float v;
    if (d < NODE_IN)                 v = nf[(size_t)(n0 + g) * NODE_IN + d];
    else if (d < NODE_IN + EDGE_IN)  v = 0.f;
    else                             v = cosf(sPH[d - (NODE_IN + EDGE_IN)]);
    sQ[g][d] = v;
  }
  __syncthreads();

  // ---------------- P1: qh[g][j] = q[g] . w_qs[j]  (128 threads, 4 j each) ----
  if (tid < 128) {
    const int j0 = tid * 4;
    float acc[4][G] = {};
    for (int c = 0; c < D_MODEL / 4; ++c) {
      float4 q4[G];
      #pragma unroll
      for (int g2 = 0; g2 < G; ++g2)
        q4[g2] = reinterpret_cast<const float4*>(&sQ[g2][0])[c];
      #pragma unroll
      for (int r = 0; r < 4; ++r) {
        float4 w4 = reinterpret_cast<const float4*>(wq + (size_t)(j0 + r) * D_MODEL)[c];
        #pragma unroll
        for (int g2 = 0; g2 < G; ++g2)
          acc[r][g2] += q4[g2].x*w4.x + q4[g2].y*w4.y + q4[g2].z*w4.z + q4[g2].w*w4.w;
      }
    }
    #pragma unroll
    for (int r = 0; r < 4; ++r)
      #pragma unroll
      for (int g2 = 0; g2 < G; ++g2)
        sQH[g2][j0 + r] = acc[r][g2];
  }
  __syncthreads();

  // ---------------- P2: qk[g][h][d] = sum_dk qh[g][h*64+dk] * w_ks[h*64+dk][d]
  {
    const int h  = tid >> 6;
    const int d0 = (tid & 63) * 5;
    float acc[5][G] = {};
    const float* wbase = wk + (size_t)h * D_K * D_MODEL + d0;
    for (int dk4 = 0; dk4 < D_K / 4; ++dk4) {
      float4 qv[G];
      #pragma unroll
      for (int g2 = 0; g2 < G; ++g2)
        qv[g2] = *reinterpret_cast<const float4*>(&sQH[g2][h * D_K + dk4 * 4]);
      #pragma unroll
      for (int s = 0; s < 4; ++s) {
        const float* wrow = wbase + (size_t)(dk4 * 4 + s) * D_MODEL;
        float w0 = wrow[0], w1 = wrow[1], w2 = wrow[2], w3 = wrow[3], w4r = wrow[4];
        float q0 = ((const float*)&qv[0])[s];
        float q1 = ((const float*)&qv[1])[s];
        float q2 = ((const float*)&qv[2])[s];
        float q3 = ((const float*)&qv[3])[s];
        acc[0][0] += w0*q0; acc[0][1] += w0*q1; acc[0][2] += w0*q2; acc[0][3] += w0*q3;
        acc[1][0] += w1*q0; acc[1][1] += w1*q1; acc[1][2] += w1*q2; acc[1][3] += w1*q3;
        acc[2][0] += w2*q0; acc[2][1] += w2*q1; acc[2][2] += w2*q2; acc[2][3] += w2*q3;
        acc[3][0] += w3*q0; acc[3][1] += w3*q1; acc[3][2] += w3*q2; acc[3][3] += w3*q3;
        acc[4][0] += w4r*q0; acc[4][1] += w4r*q1; acc[4][2] += w4r*q2; acc[4][3] += w4r*q3;
      }
    }
    #pragma unroll
    for (int dl = 0; dl < 5; ++dl)
      #pragma unroll
      for (int g2 = 0; g2 < G; ++g2)
        sB[g2][h][d0 + dl] = f2bf(acc[dl][g2]);
  }
  __syncthreads();

  // ---------------- P3: per node — build m, scores, softmax, mbar ------------
  for (int g = 0; g < G; ++g) {
    if (tid < KNB) sNI[tid] = nidx[(size_t)(n0 + g) * KNB + tid];
    if (tid < LNB) sDT[tid] = dtp[(size_t)(n0 + g) * LNB + tid];
    __syncthreads();
    // build m[l][d] = [h_nb(128) | edge(64) | cos(dt*f+p)(128)]  (bf16)
    for (int idx = tid; idx < LNB * D_MODEL; idx += BLK) {
      int l = idx / D_MODEL, d = idx - l * D_MODEL;
      float v;
      if (d < NODE_IN) {
        v = nf[(size_t)sNI[l >> 1] * NODE_IN + d];
      } else if (d < NODE_IN + EDGE_IN) {
        v = ef[((size_t)(n0 + g) * LNB + l) * EDGE_IN + (d - NODE_IN)];
      } else {
        int dd = d - (NODE_IN + EDGE_IN);
        v = cosf(sDT[l] * sFP[dd] + sPH[dd]);
      }
      u.m[l][d] = f2bf(v);
    }
    __syncthreads();
    // scores[h][l] = (m[l] . qk[h]) / 8
    if (tid < N_HEAD * LNB) {
      int h = tid >> 5, l = tid & 31;
      const uint4* mr = reinterpret_cast<const uint4*>(&u.m[l][0]);
      const uint4* br = reinterpret_cast<const uint4*>(&sB[g][h][0]);
      float acc = 0.f;
      for (int c = 0; c < D_MODEL / 8; ++c) {
        uint4 mv = mr[c], bv = br[c];
        float2 a0 = bf2f2(mv.x), a1 = bf2f2(mv.y), a2 = bf2f2(mv.z), a3 = bf2f2(mv.w);
        float2 b0 = bf2f2(bv.x), b1 = bf2f2(bv.y), b2 = bf2f2(bv.z), b3 = bf2f2(bv.w);
        acc += a0.x*b0.x + a0.y*b0.y + a1.x*b1.x + a1.y*b1.y
             + a2.x*b2.x + a2.y*b2.y + a3.x*b3.x + a3.y*b3.y;
      }
      sATT[h][l] = acc * 0.125f;
    }
    __syncthreads();
    // softmax over l (tiny: 8 threads)
    if (tid < N_HEAD) {
      int h = tid;
      float mx = -1e30f;
      for (int l = 0; l < LNB; ++l) mx = fmaxf(mx, sATT[h][l]);
      float s = 0.f;
      for (int l = 0; l < LNB; ++l) { float e = expf(sATT[h][l] - mx); sATT[h][l] = e; s += e; }
      float inv = 1.f / s;
      for (int l = 0; l < LNB; ++l) sATT[h][l] *= inv;
    }
    __syncthreads();
    // mbar[h][d] = sum_l attn[h][l]*m[l][d]  -> overwrite sB[g]
    if (tid < N_HEAD * (D_MODEL / 8)) {
      int h = tid / (D_MODEL / 8), d0 = (tid - h * (D_MODEL / 8)) * 8;
      float a[8] = {};
      for (int l = 0; l < LNB; ++l) {
        float at = sATT[h][l];
        uint4 mv = *reinterpret_cast<const uint4*>(&u.m[l][d0]);
        float2 m0 = bf2f2(mv.x), m1 = bf2f2(mv.y), m2 = bf2f2(mv.z), m3 = bf2f2(mv.w);
        a[0] += at*m0.x; a[1] += at*m0.y; a[2] += at*m1.x; a[3] += at*m1.y;
        a[4] += at*m2.x; a[5] += at*m2.y; a[6] += at*m3.x; a[7] += at*m3.y;
      }
      unsigned short* dst = &sB[g][h][d0];
      #pragma unroll
      for (int r = 0; r < 8; ++r) dst[r] = f2bf(a[r]);
    }
    __syncthreads();
  }

  // ---------------- P4: ctx[g][j] = mbar[g][h(j)] . w_vs[j] ------------------
  float ctxacc[2][G] = {};
  if (tid < 256) {
    const int j0 = tid * 2, h = j0 >> 6;
    const float4* w0 = reinterpret_cast<const float4*>(wv + (size_t)j0 * D_MODEL);
    const float4* w1 = reinterpret_cast<const float4*>(wv + (size_t)(j0 + 1) * D_MODEL);
    for (int c = 0; c < D_MODEL / 8; ++c) {
      float bm[G][8];
      #pragma unroll
      for (int g2 = 0; g2 < G; ++g2) {
        uint4 bv = *reinterpret_cast<const uint4*>(&sB[g2][h][c * 8]);
        float2 x0 = bf2f2(bv.x), x1 = bf2f2(bv.y), x2 = bf2f2(bv.z), x3 = bf2f2(bv.w);
        bm[g2][0] = x0.x; bm[g2][1] = x0.y; bm[g2][2] = x1.x; bm[g2][3] = x1.y;
        bm[g2][4] = x2.x; bm[g2][5] = x2.y; bm[g2][6] = x3.x; bm[g2][7] = x3.y;
      }
      float4 wa0 = w0[2*c], wb0 = w0[2*c + 1];
      float4 wa1 = w1[2*c], wb1 = w1[2*c + 1];
      #pragma unroll
      for (int g2 = 0; g2 < G; ++g2) {
        ctxacc[0][g2] += bm[g2][0]*wa0.x + bm[g2][1]*wa0.y + bm[g2][2]*wa0.z + bm[g2][3]*wa0.w
                       + bm[g2][4]*wb0.x + bm[g2][5]*wb0.y + bm[g2][6]*wb0.z + bm[g2][7]*wb0.w;
        ctxacc[1][g2] += bm[g2][0]*wa1.x + bm[g2][1]*wa1.y + bm[g2][2]*wa1.z + bm[g2][3]*wa1.w
                       + bm[g2][4]*wb1.x + bm[g2][5]*wb1.y + bm[g2][6]*wb1.z + bm[g2][7]*wb1.w;
      }
    }
  }
  __syncthreads();   // everyone done reading mbar before sB is reused for ctx
  if (tid < 256) {
    const int j0 = tid * 2;
    #pragma unroll
    for (int g2 = 0; g2 < G; ++g2) {
      unsigned short* cb = &sB[g2][0][0];   // flat [G][2560] region, first 512 = ctx bf16
      cb[j0]     = f2bf(ctxacc[0][g2]);
      cb[j0 + 1] = f2bf(ctxacc[1][g2]);
    }
  }
  __syncthreads();

  // ---------------- P5: x = ctx @ fc_w.T + fc_b + q  (into u.post.x) ---------
  if (tid < 160) {
    const int c0 = tid * 2;
    float acc[2][G] = {};
    const float4* fw0 = reinterpret_cast<const float4*>(fcw + (size_t)c0 * NHD);
    const float4* fw1 = reinterpret_cast<const float4*>(fcw + (size_t)(c0 + 1) * NHD);
    for (int c = 0; c < NHD / 8; ++c) {
      float cm[G][8];
      #pragma unroll
      for (int g2 = 0; g2 < G; ++g2) {
        uint4 bv = *reinterpret_cast<const uint4*>(&sB[g2][0][0] + c * 8);
        float2 x0 = bf2f2(bv.x), x1 = bf2f2(bv.y), x2 = bf2f2(bv.z), x3 = bf2f2(bv.w);
        cm[g2][0] = x0.x; cm[g2][1] = x0.y; cm[g2][2] = x1.x; cm[g2][3] = x1.y;
        cm[g2][4] = x2.x; cm[g2][5] = x2.y; cm[g2][6] = x3.x; cm[g2][7] = x3.y;
      }
      float4 wa0 = fw0[2*c], wb0 = fw0[2*c + 1];
      float4 wa1 = fw1[2*c], wb1 = fw1[2*c + 1];
      #pragma unroll
      for (int g2 = 0; g2 < G; ++g2) {
        acc[0][g2] += cm[g2][0]*wa0.x + cm[g2][1]*wa0.y + cm[g2][2]*wa0.z + cm[g2][3]*wa0.w
                    + cm[g2][4]*wb0.x + cm[g2][5]*wb0.y + cm[g2][6]*wb0.z + cm[g2][7]*wb0.w;
        acc[1][g2] += cm[g2][0]*wa1.x + cm[g2][1]*wa1.y + cm[g2][2]*wa1.z + cm[g2][3]*wa1.w
                    + cm[g2][4]*wb1.x + cm[g2][5]*wb1.y + cm[g2][6]*wb1.z + cm[g2][7]*wb1.w;
      }
    }
    #pragma unroll
    for (int r = 0; r < 2; ++r) {
      int c = c0 + r;
      float fb = fcb[c];
      #pragma unroll
      for (int g2 = 0; g2 < G; ++g2)
        u.post.x[g2][c] = acc[r][g2] + fb + sQ[g2][c];
    }
  }
  __syncthreads();

  // ---------------- LN over 320 (4 groups of 128 threads) --------------------
  {
    int g = tid >> 7, i = tid & 127;
    float s = 0.f, s2 = 0.f;
    for (int d = i; d < D_MODEL; d += 128) { float v = u.post.x[g][d]; s += v; s2 += v*v; }
    u.post.red[tid] = s;
    u.post.red[BLK + tid] = s2;
  }
  for (int off = 64; off; off >>= 1) {
    __syncthreads();
    if ((tid & 127) < off) {
      u.post.red[tid]       += u.post.red[tid + off];
      u.post.red[BLK + tid] += u.post.red[BLK + tid + off];
    }
  }
  __syncthreads();
  for (int idx = tid; idx < G * D_MODEL; idx += BLK) {
    int g = idx / D_MODEL, d = idx - g * D_MODEL;
    float mean = u.post.red[g << 7] * (1.0f / D_MODEL);
    float msq  = u.post.red[BLK + (g << 7)] * (1.0f / D_MODEL);
    float var  = msq - mean * mean;
    float v = (u.post.x[g][d] - mean) * rsqrtf(var + 1e-5f);
    u.post.x[g][d] = lng[d] * v + lnb_[d];
  }
  __syncthreads();

  // ---------------- P6: y = relu([h_dst | h_neigh] @ node_w.T + node_b) ------
  {
    int g = tid >> 7, o = tid & 127;
    float acc = 0.f;
    const float4* wr = reinterpret_cast<const float4*>(nw + (size_t)o * IN2);
    const float4* hq = reinterpret_cast<const float4*>(&sQ[g][0]);
    for (int c = 0; c < NODE_IN / 4; ++c) {
      float4 w4 = wr[c], h4 = hq[c];
      acc += h4.x*w4.x + h4.y*w4.y + h4.z*w4.z + h4.w*w4.w;
    }
    const float4* hx = reinterpret_cast<const float4*>(&u.post.x[g][0]);
    for (int c = 0; c < D_MODEL / 4; ++c) {
      float4 w4 = wr[NODE_IN / 4 + c], h4 = hx[c];
      acc += h4.x*w4.x + h4.y*w4.y + h4.z*w4.z + h4.w*w4.w;
    }
    acc += nbias[o];
    out[(size_t)(n0 + g) * HID + o] = fmaxf(acc, 0.f);
  }
}

extern "C" void kernel_launch(void* const* d_in, const int* in_sizes, int n_in,
                              void* d_out, int out_size, void* d_ws, size_t ws_size,
                              hipStream_t stream) {
  const float* nf   = (const float*)d_in[0];
  const float* ef   = (const float*)d_in[1];
  const float* dtp  = (const float*)d_in[2];
  const int*   nidx = (const int*)  d_in[3];
  const float* freq = (const float*)d_in[4];
  const float* ph   = (const float*)d_in[5];
  const float* wq   = (const float*)d_in[6];
  const float* wk   = (const float*)d_in[7];
  const float* wv   = (const float*)d_in[8];
  const float* fcw  = (const float*)d_in[9];
  const float* fcb  = (const float*)d_in[10];
  const float* lng  = (const float*)d_in[11];
  const float* lnb_ = (const float*)d_in[12];
  const float* nw   = (const float*)d_in[13];
  const float* nb   = (const float*)d_in[14];
  float* out = (float*)d_out;

  dim3 grid(N_DSTN / G);
  tgat_fused<<<grid, BLK, 0, stream>>>(nf, ef, dtp, nidx, freq, ph,
                                       wq, wk, wv, fcw, fcb, lng, lnb_, nw, nb, out);
}

// Round 2
// 924.112 us; speedup vs baseline: 1.2059x; 1.2059x over previous
//
#include <hip/hip_runtime.h>
#include <math.h>

#define LNB      32          // K*T
#define NODE_IN  128
#define EDGE_IN  64
#define TIME_D   128
#define D_MODEL  320
#define N_HEAD   8
#define D_K      64
#define NHD      512         // N_HEAD*D_K
#define HID      128
#define IN2      448         // 2*NODE_IN + TIME_D + EDGE_IN
#define N_DSTN   8192
#define G        4           // nodes per block
#define BLK      512
#define MSTR     328         // m row stride in shorts: 656B, 16B-aligned, 4-way-max banks

// ---- bf16 helpers ----
__device__ __forceinline__ float2 bf2f2(unsigned u) {
  union { unsigned i; float f; } lo, hi;
  lo.i = u << 16;
  hi.i = u & 0xffff0000u;
  return make_float2(lo.f, hi.f);
}
__device__ __forceinline__ unsigned short f2bf(float f) {
  union { float f; unsigned i; } v; v.f = f;
  unsigned x = v.i;
  return (unsigned short)((x + 0x7fffu + ((x >> 16) & 1u)) >> 16); // RTNE
}
__device__ __forceinline__ void up8(uint4 v, float* o) {
  float2 a = bf2f2(v.x), b = bf2f2(v.y), c = bf2f2(v.z), d = bf2f2(v.w);
  o[0]=a.x; o[1]=a.y; o[2]=b.x; o[3]=b.y; o[4]=c.x; o[5]=c.y; o[6]=d.x; o[7]=d.y;
}

struct PostT { float x[G][D_MODEL]; float red[8][2]; };   // 5120 + 64 B
union  MU    { unsigned short m[LNB][MSTR]; PostT post; }; // 20992 B (m dead before post)
union  QA    { unsigned short qh[G][NHD]; float att[N_HEAD][LNB]; }; // 4096 B (qh dead before att)

// LDS: sQ 5120 + QA 4096 + sB 20480 + MU 20992 + sFP/sPH 1024 = 51712 B -> 3 blocks/CU
__global__ __launch_bounds__(BLK, 6)
void tgat_fused(const float* __restrict__ nf, const float* __restrict__ ef,
                const float* __restrict__ dtp, const int* __restrict__ nidx,
                const float* __restrict__ freq, const float* __restrict__ ph,
                const float* __restrict__ wq, const float* __restrict__ wk,
                const float* __restrict__ wv, const float* __restrict__ fcw,
                const float* __restrict__ fcb, const float* __restrict__ lng,
                const float* __restrict__ lnb_, const float* __restrict__ nw,
                const float* __restrict__ nbias, float* __restrict__ out)
{
  const int tid = threadIdx.x;
  const int n0  = blockIdx.x * G;

  __shared__ alignas(16) float sQ[G][D_MODEL];
  __shared__ alignas(16) QA qa;
  __shared__ alignas(16) unsigned short sB[G][N_HEAD][D_MODEL]; // qk -> mbar -> ctx
  __shared__ alignas(16) MU u;
  __shared__ float sFP[TIME_D], sPH[TIME_D];

  // ---------------- P0: constants + q = [h_dst | 0(64) | cos(phase)] ---------
  if (tid < TIME_D) { sFP[tid] = freq[tid]; sPH[tid] = ph[tid]; }
  __syncthreads();
  for (int idx = tid; idx < G * D_MODEL; idx += BLK) {
    int g = idx / D_MODEL, d = idx - g * D_MODEL;
    float v;
    if (d < NODE_IN)                 v = nf[(size_t)(n0 + g) * NODE_IN + d];
    else if (d < NODE_IN + EDGE_IN)  v = 0.f;
    else                             v = __cosf(sPH[d - 192]);
    sQ[g][d] = v;
  }
  __syncthreads();

  // ---------------- P1: qh[g][j] = q[g] . w_qs[j]   (all 512 threads, j=tid) -
  {
    const int j = tid;
    const float4* wr = reinterpret_cast<const float4*>(wq + (size_t)j * D_MODEL);
    float acc[G] = {};
    #pragma unroll 2
    for (int c = 0; c < D_MODEL / 4; ++c) {
      float4 w4 = wr[c];
      #pragma unroll
      for (int g = 0; g < G; ++g) {
        float4 q4 = reinterpret_cast<const float4*>(sQ[g])[c]; // LDS broadcast
        acc[g] += q4.x*w4.x + q4.y*w4.y + q4.z*w4.z + q4.w*w4.w;
      }
    }
    #pragma unroll
    for (int g = 0; g < G; ++g) qa.qh[g][j] = f2bf(acc[g]);
  }
  __syncthreads();

  // ---------------- P2: qk[g][h][d] = sum_dk qh[g][h*64+dk] * wk[h*64+dk][d] -
  // thread -> (h = tid>>6, d = (tid&63) + 64*i, i<5); coalesced wk columns
  {
    const int h = tid >> 6, dl = tid & 63;
    const float* wbase = wk + (size_t)h * D_K * D_MODEL + dl;
    const unsigned* qp0 = reinterpret_cast<const unsigned*>(&qa.qh[0][h * D_K]);
    const unsigned* qp1 = reinterpret_cast<const unsigned*>(&qa.qh[1][h * D_K]);
    const unsigned* qp2 = reinterpret_cast<const unsigned*>(&qa.qh[2][h * D_K]);
    const unsigned* qp3 = reinterpret_cast<const unsigned*>(&qa.qh[3][h * D_K]);
    float acc[5][G] = {};
    for (int dk2 = 0; dk2 < D_K / 2; ++dk2) {
      float2 qv0 = bf2f2(qp0[dk2]), qv1 = bf2f2(qp1[dk2]);
      float2 qv2 = bf2f2(qp2[dk2]), qv3 = bf2f2(qp3[dk2]);
      const float* w0 = wbase + (size_t)(2 * dk2) * D_MODEL;
      const float* w1 = w0 + D_MODEL;
      #pragma unroll
      for (int i = 0; i < 5; ++i) {
        float wa = w0[i * 64], wb = w1[i * 64];
        acc[i][0] += wa * qv0.x + wb * qv0.y;
        acc[i][1] += wa * qv1.x + wb * qv1.y;
        acc[i][2] += wa * qv2.x + wb * qv2.y;
        acc[i][3] += wa * qv3.x + wb * qv3.y;
      }
    }
    #pragma unroll
    for (int i = 0; i < 5; ++i)
      #pragma unroll
      for (int g = 0; g < G; ++g)
        sB[g][h][dl + 64 * i] = f2bf(acc[i][g]);
  }
  __syncthreads();

  // ---------------- P3: per node — m build, scores(+softmax), mbar -----------
  for (int g = 0; g < G; ++g) {
    const int nb = n0 + g;
    // build m (bf16): [h_nb(128) | edge(64) | cos(dt*f+p)(128)]
    #pragma unroll 1
    for (int k = 0; k < (LNB * D_MODEL) / BLK; ++k) {   // 20 iters
      int idx = k * BLK + tid;
      int l = idx / D_MODEL, d = idx - l * D_MODEL;
      float v;
      if (d < NODE_IN) {
        int ni = nidx[(size_t)nb * 16 + (l >> 1)];
        v = nf[(size_t)ni * NODE_IN + d];
      } else if (d < NODE_IN + EDGE_IN) {
        v = ef[((size_t)nb * LNB + l) * EDGE_IN + (d - NODE_IN)];
      } else {
        int dd = d - 192;
        v = __cosf(dtp[(size_t)nb * LNB + l] * sFP[dd] + sPH[dd]);
      }
      u.m[l][d] = f2bf(v);
    }
    __syncthreads();
    // scores + in-register softmax (32-lane butterfly per head)
    if (tid < N_HEAD * LNB) {
      int h = tid >> 5, l = tid & 31;
      const uint4* mr = reinterpret_cast<const uint4*>(u.m[l]);
      const uint4* br = reinterpret_cast<const uint4*>(sB[g][h]);
      float acc = 0.f;
      for (int c = 0; c < D_MODEL / 8; ++c) {
        float a[8], b[8];
        up8(mr[c], a); up8(br[c], b);
        #pragma unroll
        for (int i = 0; i < 8; ++i) acc += a[i] * b[i];
      }
      float s = acc * 0.125f;
      float mx = s;
      #pragma unroll
      for (int off = 16; off >= 1; off >>= 1) mx = fmaxf(mx, __shfl_xor(mx, off));
      float e = __expf(s - mx);
      float sm = e;
      #pragma unroll
      for (int off = 16; off >= 1; off >>= 1) sm += __shfl_xor(sm, off);
      qa.att[h][l] = e / sm;      // qh region is dead; alias is safe
    }
    __syncthreads();
    // mbar[h][d] = sum_l attn[h][l] * m[l][d]  -> overwrite sB[g]
    if (tid < 320) {
      int h = tid / 40, ch = tid - h * 40;
      int d0 = ch * 8;
      float a[8] = {};
      for (int l = 0; l < LNB; ++l) {
        float at = qa.att[h][l];
        float mv[8]; up8(*reinterpret_cast<const uint4*>(&u.m[l][d0]), mv);
        #pragma unroll
        for (int i = 0; i < 8; ++i) a[i] += at * mv[i];
      }
      #pragma unroll
      for (int i = 0; i < 8; ++i) sB[g][h][d0 + i] = f2bf(a[i]);
    }
    __syncthreads();
  }

  // ---------------- P4: ctx[g][j] = mbar[g][h(j)] . wv[j]  (j = tid) ---------
  {
    const int j = tid, h = tid >> 6;
    const float4* wr = reinterpret_cast<const float4*>(wv + (size_t)j * D_MODEL);
    float acc[G] = {};
    for (int c = 0; c < D_MODEL / 8; ++c) {
      float4 wa = wr[2 * c], wb = wr[2 * c + 1];
      #pragma unroll
      for (int g = 0; g < G; ++g) {
        float b[8]; up8(*reinterpret_cast<const uint4*>(&sB[g][h][c * 8]), b); // broadcast
        acc[g] += b[0]*wa.x + b[1]*wa.y + b[2]*wa.z + b[3]*wa.w
                + b[4]*wb.x + b[5]*wb.y + b[6]*wb.z + b[7]*wb.w;
      }
    }
    __syncthreads();   // all mbar reads done before sB is reused for ctx
    #pragma unroll
    for (int g = 0; g < G; ++g) (&sB[g][0][0])[j] = f2bf(acc[g]);
  }
  __syncthreads();

  // ---------------- P5: x[g][c] = ctx[g] . fcw[c] + fcb[c] + q[g][c] ---------
  if (tid < D_MODEL) {
    const int c = tid;
    const float4* fw = reinterpret_cast<const float4*>(fcw + (size_t)c * NHD);
    float acc[G] = {};
    for (int k = 0; k < NHD / 8; ++k) {
      float4 wa = fw[2 * k], wb = fw[2 * k + 1];
      #pragma unroll
      for (int g = 0; g < G; ++g) {
        float cv[8]; up8(reinterpret_cast<const uint4*>(&sB[g][0][0])[k], cv); // broadcast
        acc[g] += cv[0]*wa.x + cv[1]*wa.y + cv[2]*wa.z + cv[3]*wa.w
                + cv[4]*wb.x + cv[5]*wb.y + cv[6]*wb.z + cv[7]*wb.w;
      }
    }
    float fb = fcb[c];
    #pragma unroll
    for (int g = 0; g < G; ++g) u.post.x[g][c] = acc[g] + fb + sQ[g][c];
  }
  __syncthreads();

  // ---------------- LN over 320 (2 waves per node, shuffle reduce) -----------
  {
    int g = tid >> 7, i = tid & 127;
    float s = 0.f, s2 = 0.f;
    for (int d = i; d < D_MODEL; d += 128) { float v = u.post.x[g][d]; s += v; s2 += v * v; }
    #pragma unroll
    for (int off = 32; off >= 1; off >>= 1) { s += __shfl_xor(s, off); s2 += __shfl_xor(s2, off); }
    int w = tid >> 6;
    if ((tid & 63) == 0) { u.post.red[w][0] = s; u.post.red[w][1] = s2; }
    __syncthreads();
    float S  = u.post.red[2 * g][0] + u.post.red[2 * g + 1][0];
    float S2 = u.post.red[2 * g][1] + u.post.red[2 * g + 1][1];
    float mean = S * (1.0f / D_MODEL);
    float var  = S2 * (1.0f / D_MODEL) - mean * mean;
    float rstd = rsqrtf(var + 1e-5f);
    for (int d = i; d < D_MODEL; d += 128) {
      float v = (u.post.x[g][d] - mean) * rstd;
      u.post.x[g][d] = lng[d] * v + lnb_[d];
    }
  }
  __syncthreads();

  // ---------------- P6: y = relu([h_dst | h_neigh] @ nw.T + nb) --------------
  {
    int g = tid >> 7, o = tid & 127;
    float acc = 0.f;
    const float4* wr = reinterpret_cast<const float4*>(nw + (size_t)o * IN2);
    const float4* hq = reinterpret_cast<const float4*>(sQ[g]);
    #pragma unroll 4
    for (int c = 0; c < NODE_IN / 4; ++c) {
      float4 w4 = wr[c], h4 = hq[c];
      acc += h4.x*w4.x + h4.y*w4.y + h4.z*w4.z + h4.w*w4.w;
    }
    const float4* hx = reinterpret_cast<const float4*>(u.post.x[g]);
    #pragma unroll 4
    for (int c = 0; c < D_MODEL / 4; ++c) {
      float4 w4 = wr[NODE_IN / 4 + c], h4 = hx[c];
      acc += h4.x*w4.x + h4.y*w4.y + h4.z*w4.z + h4.w*w4.w;
    }
    acc += nbias[o];
    out[(size_t)(n0 + g) * HID + o] = fmaxf(acc, 0.f);
  }
}

extern "C" void kernel_launch(void* const* d_in, const int* in_sizes, int n_in,
                              void* d_out, int out_size, void* d_ws, size_t ws_size,
                              hipStream_t stream) {
  const float* nf   = (const float*)d_in[0];
  const float* ef   = (const float*)d_in[1];
  const float* dtp  = (const float*)d_in[2];
  const int*   nidx = (const int*)  d_in[3];
  const float* freq = (const float*)d_in[4];
  const float* ph   = (const float*)d_in[5];
  const float* wq   = (const float*)d_in[6];
  const float* wk   = (const float*)d_in[7];
  const float* wv   = (const float*)d_in[8];
  const float* fcw  = (const float*)d_in[9];
  const float* fcb  = (const float*)d_in[10];
  const float* lng  = (const float*)d_in[11];
  const float* lnb_ = (const float*)d_in[12];
  const float* nw   = (const float*)d_in[13];
  const float* nb   = (const float*)d_in[14];
  float* out = (float*)d_out;

  dim3 grid(N_DSTN / G);
  tgat_fused<<<grid, BLK, 0, stream>>>(nf, ef, dtp, nidx, freq, ph,
                                       wq, wk, wv, fcw, fcb, lng, lnb_, nw, nb, out);
}

// Round 3
// 546.226 us; speedup vs baseline: 2.0402x; 1.6918x over previous
//
#include <hip/hip_runtime.h>
#include <math.h>

#define LNB      32
#define NODE_IN  128
#define EDGE_IN  64
#define TIME_D   128
#define D_MODEL  320
#define N_HEAD   8
#define D_K      64
#define NHD      512
#define HID      128
#define IN2      448
#define N_DSTN   8192
#define G        16
#define BLK      512

typedef __attribute__((ext_vector_type(8))) short bf16x8;
typedef __attribute__((ext_vector_type(4))) float f32x4;
#define MFMA16(a,b,c) __builtin_amdgcn_mfma_f32_16x16x32_bf16(a,b,c,0,0,0)

// ---- LDS layout (bytes). All lane-varying row strides are odd multiples of 16B.
#define OFF_Q    0        // u16 [16][328]   q bf16                     10,496
#define OFF_QH   10496    // u16 [16][520]   qh -> ctx (alias in time)  16,640
#define OFF_QK   27136    // u16 [16] node-stride 2632, h-stride 328    84,224  (qk -> mbar)
#define OFF_M    111360   // u16 [32][328]   m row-major; later sX f32  20,992
#define OFF_MT   132352   // u16 [320][40]   m transposed; later sXb    25,600
#define OFF_ATT  157952   // u16 [16][40]                                1,280
#define OFF_FP   159232   // f32 [128]
#define OFF_PH   159744   // f32 [128]
#define OFF_Z    160256   // u16 [8] zeros
#define LDS_BYTES 160272

#define SQ_ST    328
#define SQH_ST   520
#define SQK_NST  2632
#define SQK_HST  328
#define SM_ST    328
#define SMT_ST   40
#define SATT_ST  40
#define SXB_ST   328
#define SX_ST    320   // f32

// ws (bf16) element offsets
#define WS_WQ    0
#define WS_WKT   163840
#define WS_WV    327680
#define WS_FCW   491520
#define WS_NW    655360

__device__ __forceinline__ float bf2f(unsigned short s) {
  union { unsigned i; float f; } v; v.i = ((unsigned)s) << 16; return v.f;
}
__device__ __forceinline__ unsigned short f2bf(float f) {
  union { float f; unsigned i; } v; v.f = f;
  unsigned x = v.i;
  return (unsigned short)((x + 0x7fffu + ((x >> 16) & 1u)) >> 16); // RTNE
}

__global__ __launch_bounds__(256)
void prep_weights(const float* __restrict__ wq, const float* __restrict__ wk,
                  const float* __restrict__ wv, const float* __restrict__ fcw,
                  const float* __restrict__ nw, unsigned short* __restrict__ ws)
{
  int i = blockIdx.x * 256 + threadIdx.x;          // grid = 640*256 = 163840
  ws[WS_WQ + i] = f2bf(wq[i]);
  { // wkT[h][d][dk] = wk[h*64+dk][d]
    int h = i / 20480, r = i - h * 20480, d = r >> 6, dk = r & 63;
    ws[WS_WKT + i] = f2bf(wk[(size_t)(h * 64 + dk) * D_MODEL + d]);
  }
  ws[WS_WV + i] = f2bf(wv[i]);
  ws[WS_FCW + i] = f2bf(fcw[i]);
  if (i < HID * IN2) ws[WS_NW + i] = f2bf(nw[i]);
}

__global__ __launch_bounds__(BLK, 2)
void tgat_mfma(const float* __restrict__ nf, const float* __restrict__ ef,
               const float* __restrict__ dtp, const int* __restrict__ nidx,
               const float* __restrict__ freq, const float* __restrict__ ph,
               const float* __restrict__ fcb, const float* __restrict__ lng,
               const float* __restrict__ lnb_, const float* __restrict__ nbias,
               const unsigned short* __restrict__ ws, float* __restrict__ out)
{
  extern __shared__ char lds[];
  unsigned short* sQ   = (unsigned short*)(lds + OFF_Q);
  unsigned short* sQH  = (unsigned short*)(lds + OFF_QH);
  unsigned short* sQK  = (unsigned short*)(lds + OFF_QK);
  unsigned short* sM   = (unsigned short*)(lds + OFF_M);
  unsigned short* sMT  = (unsigned short*)(lds + OFF_MT);
  unsigned short* sATT = (unsigned short*)(lds + OFF_ATT);
  float*          sFP  = (float*)(lds + OFF_FP);
  float*          sPH  = (float*)(lds + OFF_PH);
  unsigned short* sZ   = (unsigned short*)(lds + OFF_Z);
  float*          sX   = (float*)(lds + OFF_M);    // alias (sM dead after P3)
  unsigned short* sXb  = (unsigned short*)(lds + OFF_MT); // alias (sMT dead)

  const int tid  = threadIdx.x;
  const int wid  = tid >> 6;
  const int lane = tid & 63;
  const int qd   = lane >> 4;        // quad
  const int lm   = lane & 15;
  const int n0   = blockIdx.x * G;

  const unsigned short* wsWQ  = ws + WS_WQ;
  const unsigned short* wsWKT = ws + WS_WKT;
  const unsigned short* wsWV  = ws + WS_WV;
  const unsigned short* wsFCW = ws + WS_FCW;
  const unsigned short* wsNW  = ws + WS_NW;

  // ---------------- P0: constants + q = [h_dst | 0(64) | cos(phase)] ---------
  if (tid < TIME_D) { sFP[tid] = freq[tid]; sPH[tid] = ph[tid]; }
  if (tid < 8) sZ[tid] = 0;
  __syncthreads();
  for (int idx = tid; idx < G * D_MODEL; idx += BLK) {
    int n = idx / D_MODEL, d = idx - n * D_MODEL;
    float v;
    if (d < NODE_IN)      v = nf[(size_t)(n0 + n) * NODE_IN + d];
    else if (d < 192)     v = 0.f;
    else                  v = __cosf(sPH[d - 192]);
    sQ[n * SQ_ST + d] = f2bf(v);
  }
  __syncthreads();

  // ---------------- P1: qh = q @ wq^T   (M=16 nodes, N=512, K=320) -----------
  {
    f32x4 acc[4] = {{0.f,0.f,0.f,0.f},{0.f,0.f,0.f,0.f},{0.f,0.f,0.f,0.f},{0.f,0.f,0.f,0.f}};
    for (int kt = 0; kt < 10; ++kt) {
      bf16x8 a = *(const bf16x8*)&sQ[lm * SQ_ST + kt * 32 + qd * 8];
      #pragma unroll
      for (int u = 0; u < 4; ++u) {
        int j = (wid * 4 + u) * 16 + lm;
        bf16x8 b = *(const bf16x8*)&wsWQ[(size_t)j * D_MODEL + kt * 32 + qd * 8];
        acc[u] = MFMA16(a, b, acc[u]);
      }
    }
    #pragma unroll
    for (int u = 0; u < 4; ++u)
      #pragma unroll
      for (int r = 0; r < 4; ++r)
        sQH[(qd * 4 + r) * SQH_ST + (wid * 4 + u) * 16 + lm] = f2bf(acc[u][r]);
  }
  __syncthreads();

  // ---------------- P2: qk[n][h][d] (wave = head; M=16 nodes, N=320, K=64) ---
  {
    const int h = wid;
    for (int dtg = 0; dtg < 5; ++dtg) {
      f32x4 acc[4] = {{0.f,0.f,0.f,0.f},{0.f,0.f,0.f,0.f},{0.f,0.f,0.f,0.f},{0.f,0.f,0.f,0.f}};
      #pragma unroll
      for (int ks = 0; ks < 2; ++ks) {
        bf16x8 a = *(const bf16x8*)&sQH[lm * SQH_ST + h * 64 + ks * 32 + qd * 8];
        #pragma unroll
        for (int u = 0; u < 4; ++u) {
          int d = (dtg * 4 + u) * 16 + lm;
          bf16x8 b = *(const bf16x8*)&wsWKT[((size_t)h * D_MODEL + d) * 64 + ks * 32 + qd * 8];
          acc[u] = MFMA16(a, b, acc[u]);
        }
      }
      #pragma unroll
      for (int u = 0; u < 4; ++u)
        #pragma unroll
        for (int r = 0; r < 4; ++r)
          sQK[(qd * 4 + r) * SQK_NST + h * SQK_HST + (dtg * 4 + u) * 16 + lm] = f2bf(acc[u][r]);
    }
  }
  __syncthreads();

  // ---------------- P3: per node — m build, scores+softmax, mbar -------------
  for (int n = 0; n < G; ++n) {
    const int nb = n0 + n;
    // m build (both layouts)
    #pragma unroll 1
    for (int k = 0; k < 20; ++k) {
      int idx = k * BLK + tid;
      int l = idx / D_MODEL, d = idx - l * D_MODEL;
      float v;
      if (d < NODE_IN) {
        int ni = nidx[nb * 16 + (l >> 1)];
        v = nf[(size_t)ni * NODE_IN + d];
      } else if (d < 192) {
        v = ef[((size_t)nb * LNB + l) * EDGE_IN + (d - NODE_IN)];
      } else {
        int dd = d - 192;
        v = __cosf(dtp[(size_t)nb * LNB + l] * sFP[dd] + sPH[dd]);
      }
      unsigned short bv = f2bf(v);
      sM[l * SM_ST + d] = bv;
      sMT[d * SMT_ST + l] = bv;
    }
    __syncthreads();
    // scores D[l][h] = m @ qk^T (wave 0 only; 2 M-tiles, K=320)
    if (wid == 0) {
      f32x4 acc0 = {0.f,0.f,0.f,0.f}, acc1 = {0.f,0.f,0.f,0.f};
      for (int kt = 0; kt < 10; ++kt) {
        bf16x8 b;
        if (lm < 8) b = *(const bf16x8*)&sQK[n * SQK_NST + lm * SQK_HST + kt * 32 + qd * 8];
        else        b = *(const bf16x8*)sZ;
        bf16x8 a0 = *(const bf16x8*)&sM[lm * SM_ST + kt * 32 + qd * 8];
        bf16x8 a1 = *(const bf16x8*)&sM[(16 + lm) * SM_ST + kt * 32 + qd * 8];
        acc0 = MFMA16(a0, b, acc0);
        acc1 = MFMA16(a1, b, acc1);
      }
      float s[8], e[8];
      #pragma unroll
      for (int r = 0; r < 4; ++r) { s[r] = acc0[r] * 0.125f; s[4 + r] = acc1[r] * 0.125f; }
      float mx = s[0];
      #pragma unroll
      for (int i = 1; i < 8; ++i) mx = fmaxf(mx, s[i]);
      mx = fmaxf(mx, __shfl_xor(mx, 16));
      mx = fmaxf(mx, __shfl_xor(mx, 32));
      float sum = 0.f;
      #pragma unroll
      for (int i = 0; i < 8; ++i) { e[i] = __expf(s[i] - mx); sum += e[i]; }
      sum += __shfl_xor(sum, 16);
      sum += __shfl_xor(sum, 32);
      float inv = 1.f / sum;
      #pragma unroll
      for (int i = 0; i < 8; ++i) {
        int l = (i < 4) ? (qd * 4 + i) : (16 + qd * 4 + (i - 4));
        sATT[lm * SATT_ST + l] = f2bf(e[i] * inv);
      }
    }
    __syncthreads();
    // mbar[h][d] = attn @ m  (K=32, one MFMA per d-tile; overwrite qk[n])
    {
      bf16x8 a = *(const bf16x8*)&sATT[lm * SATT_ST + qd * 8];
      for (int dt = wid; dt < 20; dt += 8) {
        int d = dt * 16 + lm;
        bf16x8 b = *(const bf16x8*)&sMT[d * SMT_ST + qd * 8];
        f32x4 acc = {0.f,0.f,0.f,0.f};
        acc = MFMA16(a, b, acc);
        if (qd < 2) {
          #pragma unroll
          for (int r = 0; r < 4; ++r)
            sQK[n * SQK_NST + (qd * 4 + r) * SQK_HST + d] = f2bf(acc[r]);
        }
      }
    }
    __syncthreads();
  }

  // ---------------- P4: ctx (wave = head; M=16 nodes, N=64, K=320) -----------
  {
    const int h = wid;
    f32x4 acc[4] = {{0.f,0.f,0.f,0.f},{0.f,0.f,0.f,0.f},{0.f,0.f,0.f,0.f},{0.f,0.f,0.f,0.f}};
    for (int kt = 0; kt < 10; ++kt) {
      bf16x8 a = *(const bf16x8*)&sQK[lm * SQK_NST + h * SQK_HST + kt * 32 + qd * 8];
      #pragma unroll
      for (int u = 0; u < 4; ++u) {
        int jv = h * 64 + u * 16 + lm;
        bf16x8 b = *(const bf16x8*)&wsWV[(size_t)jv * D_MODEL + kt * 32 + qd * 8];
        acc[u] = MFMA16(a, b, acc[u]);
      }
    }
    __syncthreads();   // ensure all mbar reads done isn't needed (P3 ended with sync); this guards sQH overwrite vs P2? qh dead. Keep for safety of ctx stores ordering.
    #pragma unroll
    for (int u = 0; u < 4; ++u)
      #pragma unroll
      for (int r = 0; r < 4; ++r)
        sQH[(qd * 4 + r) * SQH_ST + h * 64 + u * 16 + lm] = f2bf(acc[u][r]);
  }
  __syncthreads();

  // ---------------- P5: x = ctx @ fcw^T + fcb + q  (M=16, N=320, K=512) ------
  {
    int ct0 = wid, ct1 = wid + 8, ct2 = wid + 16;
    f32x4 a0 = {0.f,0.f,0.f,0.f}, a1 = {0.f,0.f,0.f,0.f}, a2 = {0.f,0.f,0.f,0.f};
    int c0 = ct0 * 16 + lm, c1 = ct1 * 16 + lm, c2 = ct2 * 16 + lm;
    for (int ks = 0; ks < 16; ++ks) {
      bf16x8 a = *(const bf16x8*)&sQH[lm * SQH_ST + ks * 32 + qd * 8];
      bf16x8 b0 = *(const bf16x8*)&wsFCW[(size_t)c0 * NHD + ks * 32 + qd * 8];
      a0 = MFMA16(a, b0, a0);
      bf16x8 b1 = *(const bf16x8*)&wsFCW[(size_t)c1 * NHD + ks * 32 + qd * 8];
      a1 = MFMA16(a, b1, a1);
      if (wid < 4) {
        bf16x8 b2 = *(const bf16x8*)&wsFCW[(size_t)c2 * NHD + ks * 32 + qd * 8];
        a2 = MFMA16(a, b2, a2);
      }
    }
    float fb0 = fcb[c0], fb1 = fcb[c1];
    #pragma unroll
    for (int r = 0; r < 4; ++r) {
      int nn = qd * 4 + r;
      sX[nn * SX_ST + c0] = a0[r] + fb0 + bf2f(sQ[nn * SQ_ST + c0]);
      sX[nn * SX_ST + c1] = a1[r] + fb1 + bf2f(sQ[nn * SQ_ST + c1]);
    }
    if (wid < 4) {
      float fb2 = fcb[c2];
      #pragma unroll
      for (int r = 0; r < 4; ++r) {
        int nn = qd * 4 + r;
        sX[nn * SX_ST + c2] = a2[r] + fb2 + bf2f(sQ[nn * SQ_ST + c2]);
      }
    }
  }
  __syncthreads();

  // ---------------- LN (wave w -> nodes 2w, 2w+1), write bf16 to sXb ---------
  {
    #pragma unroll
    for (int t = 0; t < 2; ++t) {
      int nn = 2 * wid + t;
      float v[5], s = 0.f, s2 = 0.f;
      #pragma unroll
      for (int i = 0; i < 5; ++i) {
        int c = lane + 64 * i;
        v[i] = sX[nn * SX_ST + c];
        s += v[i]; s2 += v[i] * v[i];
      }
      #pragma unroll
      for (int off = 32; off >= 1; off >>= 1) {
        s += __shfl_xor(s, off); s2 += __shfl_xor(s2, off);
      }
      float mean = s * (1.f / D_MODEL);
      float var  = s2 * (1.f / D_MODEL) - mean * mean;
      float rstd = rsqrtf(var + 1e-5f);
      #pragma unroll
      for (int i = 0; i < 5; ++i) {
        int c = lane + 64 * i;
        float y = lng[c] * ((v[i] - mean) * rstd) + lnb_[c];
        sXb[nn * SXB_ST + c] = f2bf(y);
      }
    }
  }
  __syncthreads();

  // ---------------- P6: out = relu([h_dst | h_neigh] @ nw^T + nb) ------------
  {
    int o = wid * 16 + lm;
    f32x4 acc = {0.f,0.f,0.f,0.f};
    for (int ks = 0; ks < 14; ++ks) {
      bf16x8 a;
      if (ks < 4) a = *(const bf16x8*)&sQ[lm * SQ_ST + ks * 32 + qd * 8];
      else        a = *(const bf16x8*)&sXb[lm * SXB_ST + (ks - 4) * 32 + qd * 8];
      bf16x8 b = *(const bf16x8*)&wsNW[(size_t)o * IN2 + ks * 32 + qd * 8];
      acc = MFMA16(a, b, acc);
    }
    float nbv = nbias[o];
    #pragma unroll
    for (int r = 0; r < 4; ++r) {
      int nn = qd * 4 + r;
      out[(size_t)(n0 + nn) * HID + o] = fmaxf(acc[r] + nbv, 0.f);
    }
  }
}

extern "C" void kernel_launch(void* const* d_in, const int* in_sizes, int n_in,
                              void* d_out, int out_size, void* d_ws, size_t ws_size,
                              hipStream_t stream) {
  const float* nf   = (const float*)d_in[0];
  const float* ef   = (const float*)d_in[1];
  const float* dtp  = (const float*)d_in[2];
  const int*   nidx = (const int*)  d_in[3];
  const float* freq = (const float*)d_in[4];
  const float* ph   = (const float*)d_in[5];
  const float* wq   = (const float*)d_in[6];
  const float* wk   = (const float*)d_in[7];
  const float* wv   = (const float*)d_in[8];
  const float* fcw  = (const float*)d_in[9];
  const float* fcb  = (const float*)d_in[10];
  const float* lng  = (const float*)d_in[11];
  const float* lnb_ = (const float*)d_in[12];
  const float* nw   = (const float*)d_in[13];
  const float* nb   = (const float*)d_in[14];
  float* out = (float*)d_out;
  unsigned short* ws = (unsigned short*)d_ws;

  static int lds_set = 0;
  (void)lds_set;
  hipFuncSetAttribute((const void*)tgat_mfma,
                      hipFuncAttributeMaxDynamicSharedMemorySize, LDS_BYTES);

  prep_weights<<<640, 256, 0, stream>>>(wq, wk, wv, fcw, nw, ws);
  tgat_mfma<<<N_DSTN / G, BLK, LDS_BYTES, stream>>>(nf, ef, dtp, nidx, freq, ph,
                                                    fcb, lng, lnb_, nb, ws, out);
}

// Round 4
// 299.558 us; speedup vs baseline: 3.7202x; 1.8234x over previous
//
#include <hip/hip_runtime.h>
#include <math.h>

#define LNB      32
#define NODE_IN  128
#define EDGE_IN  64
#define TIME_D   128
#define D_MODEL  320
#define N_HEAD   8
#define D_K      64
#define NHD      512
#define HID      128
#define IN2      448
#define N_DSTN   8192

typedef __attribute__((ext_vector_type(8))) short bf16x8;
typedef __attribute__((ext_vector_type(4))) float f32x4;
#define MFMA16(a,b,c) __builtin_amdgcn_mfma_f32_16x16x32_bf16(a,b,c,0,0,0)

// ---- workspace layout (elements of unsigned short) ----
#define WS_WQ    0
#define WS_WKT   163840
#define WS_WV    327680
#define WS_FCW   491520
#define WS_NW    655360        // 57344 elems
#define WS_QKM   712704        // 8192*8*320 = 20,971,520 elems (qk -> mbar, in place)
// total = 21,684,224 shorts = 43.4 MB

__device__ __forceinline__ unsigned short f2bf(float f) {
  union { float f; unsigned i; } v; v.f = f;
  unsigned x = v.i;
  return (unsigned short)((x + 0x7fffu + ((x >> 16) & 1u)) >> 16); // RTNE
}

__global__ __launch_bounds__(256)
void prep_weights(const float* __restrict__ wq, const float* __restrict__ wk,
                  const float* __restrict__ wv, const float* __restrict__ fcw,
                  const float* __restrict__ nw, unsigned short* __restrict__ ws)
{
  int i = blockIdx.x * 256 + threadIdx.x;          // grid = 640*256 = 163840
  ws[WS_WQ + i] = f2bf(wq[i]);
  { // wkT[h][d][dk] = wk[h*64+dk][d]
    int h = i / 20480, r = i - h * 20480, d = r >> 6, dk = r & 63;
    ws[WS_WKT + i] = f2bf(wk[(size_t)(h * 64 + dk) * D_MODEL + d]);
  }
  ws[WS_WV + i] = f2bf(wv[i]);
  ws[WS_FCW + i] = f2bf(fcw[i]);
  if (i < HID * IN2) ws[WS_NW + i] = f2bf(nw[i]);
}

// =================== K2: qh = q@wq^T ; qk[n][h][d] ==========================
// grid 512 x 256 thr, G=16 nodes/block. LDS ~28 KB -> 5 blocks/CU.
__global__ __launch_bounds__(256, 4)
void tgat_qk(const float* __restrict__ nf, const float* __restrict__ ph,
             const unsigned short* __restrict__ ws, unsigned short* __restrict__ qkm)
{
  __shared__ alignas(16) unsigned short sQ[16 * 328];   // 10.5 KB
  __shared__ alignas(16) unsigned short sQH[16 * 520];  // 16.6 KB
  __shared__ float cph[TIME_D];

  const int tid = threadIdx.x;
  const int wid = tid >> 6, lane = tid & 63, qd = lane >> 4, lm = lane & 15;
  const int n0 = blockIdx.x * 16;
  const unsigned short* wsWQ  = ws + WS_WQ;
  const unsigned short* wsWKT = ws + WS_WKT;

  if (tid < TIME_D) cph[tid] = __cosf(ph[tid]);
  __syncthreads();
  for (int k = 0; k < 20; ++k) {                 // 16*320 / 256
    int idx = k * 256 + tid;
    int n = idx / D_MODEL, d = idx - n * D_MODEL;
    float v;
    if (d < NODE_IN)      v = nf[(size_t)(n0 + n) * NODE_IN + d];
    else if (d < 192)     v = 0.f;
    else                  v = cph[d - 192];
    sQ[n * 328 + d] = f2bf(v);
  }
  __syncthreads();

  // qh: M=16, N=512, K=320; wave w -> 8 N-tiles
  {
    f32x4 acc[8] = {};
    for (int kt = 0; kt < 10; ++kt) {
      bf16x8 a = *(const bf16x8*)&sQ[lm * 328 + kt * 32 + qd * 8];
      #pragma unroll
      for (int u = 0; u < 8; ++u) {
        int j = (wid * 8 + u) * 16 + lm;
        bf16x8 b = *(const bf16x8*)&wsWQ[(size_t)j * D_MODEL + kt * 32 + qd * 8];
        acc[u] = MFMA16(a, b, acc[u]);
      }
    }
    #pragma unroll
    for (int u = 0; u < 8; ++u)
      #pragma unroll
      for (int r = 0; r < 4; ++r)
        sQH[(qd * 4 + r) * 520 + (wid * 8 + u) * 16 + lm] = f2bf(acc[u][r]);
  }
  __syncthreads();

  // qk: per head M=16, N=320, K=64; wave w -> heads {w, w+4}
  #pragma unroll
  for (int t = 0; t < 2; ++t) {
    const int h = wid + 4 * t;
    bf16x8 a0 = *(const bf16x8*)&sQH[lm * 520 + h * 64 + qd * 8];
    bf16x8 a1 = *(const bf16x8*)&sQH[lm * 520 + h * 64 + 32 + qd * 8];
    for (int dt = 0; dt < 20; ++dt) {
      int d = dt * 16 + lm;
      bf16x8 b0 = *(const bf16x8*)&wsWKT[((size_t)h * D_MODEL + d) * 64 + qd * 8];
      bf16x8 b1 = *(const bf16x8*)&wsWKT[((size_t)h * D_MODEL + d) * 64 + 32 + qd * 8];
      f32x4 acc = {};
      acc = MFMA16(a0, b0, acc);
      acc = MFMA16(a1, b1, acc);
      #pragma unroll
      for (int r = 0; r < 4; ++r)
        qkm[(size_t)(n0 + qd * 4 + r) * 2560 + h * D_MODEL + d] = f2bf(acc[r]);
    }
  }
}

// =================== K3: attention (1 node / 256-thr block) =================
// LDS ~49 KB -> 3 blocks/CU; 8192 blocks. 2 barriers after setup.
__global__ __launch_bounds__(256, 3)
void tgat_attn(const float* __restrict__ nf, const float* __restrict__ ef,
               const float* __restrict__ dtp, const int* __restrict__ nidx,
               const float* __restrict__ freq, const float* __restrict__ ph,
               unsigned short* __restrict__ qkm)
{
  __shared__ alignas(16) unsigned short sM [LNB * 328];    // 20.5 KB row-major
  __shared__ alignas(16) unsigned short sMT[D_MODEL * 40]; // 25.6 KB col-major
  __shared__ alignas(16) unsigned short sATT[16 * 40];     // 1.28 KB
  __shared__ float sFP[TIME_D], sPH[TIME_D], sDT[LNB];
  __shared__ int   sNI[16];

  const int tid = threadIdx.x;
  const int wid = tid >> 6, lane = tid & 63, qd = lane >> 4, lm = lane & 15;
  const int n = blockIdx.x;

  if (tid < TIME_D) { sFP[tid] = freq[tid]; sPH[tid] = ph[tid]; }
  if (tid < 16)  sNI[tid] = nidx[n * 16 + tid];
  if (tid < LNB) sDT[tid] = dtp[(size_t)n * LNB + tid];
  __syncthreads();

  // m build: thread -> (l = g&31, d-group g>>5 of 8 consecutive d)
  #pragma unroll 1
  for (int it = 0; it < 5; ++it) {
    int g = it * 256 + tid;
    int l = g & 31, dg = g >> 5;
    int d0 = dg * 8;
    float v[8];
    if (dg < 16) {
      const float4* src = (const float4*)(nf + (size_t)sNI[l >> 1] * NODE_IN + d0);
      float4 f0 = src[0], f1 = src[1];
      v[0]=f0.x; v[1]=f0.y; v[2]=f0.z; v[3]=f0.w; v[4]=f1.x; v[5]=f1.y; v[6]=f1.z; v[7]=f1.w;
    } else if (dg < 24) {
      const float4* src = (const float4*)(ef + ((size_t)n * LNB + l) * EDGE_IN + (d0 - NODE_IN));
      float4 f0 = src[0], f1 = src[1];
      v[0]=f0.x; v[1]=f0.y; v[2]=f0.z; v[3]=f0.w; v[4]=f1.x; v[5]=f1.y; v[6]=f1.z; v[7]=f1.w;
    } else {
      int dd = d0 - 192;
      float dt = sDT[l];
      #pragma unroll
      for (int j = 0; j < 8; ++j) v[j] = __cosf(dt * sFP[dd + j] + sPH[dd + j]);
    }
    unsigned short b8[8];
    #pragma unroll
    for (int j = 0; j < 8; ++j) b8[j] = f2bf(v[j]);
    *(bf16x8*)&sM[l * 328 + d0] = *(const bf16x8*)b8;
    #pragma unroll
    for (int j = 0; j < 8; ++j) sMT[(d0 + j) * 40 + l] = b8[j];
  }
  __syncthreads();

  // scores + softmax (wave 0): D[l][h] = m @ qk^T / 8
  if (wid == 0) {
    const unsigned short* qn = qkm + (size_t)n * 2560;
    f32x4 acc0 = {}, acc1 = {};
    for (int kt = 0; kt < 10; ++kt) {
      bf16x8 b = {0,0,0,0,0,0,0,0};
      if (lm < 8) b = *(const bf16x8*)&qn[lm * D_MODEL + kt * 32 + qd * 8];
      bf16x8 a0 = *(const bf16x8*)&sM[lm * 328 + kt * 32 + qd * 8];
      bf16x8 a1 = *(const bf16x8*)&sM[(16 + lm) * 328 + kt * 32 + qd * 8];
      acc0 = MFMA16(a0, b, acc0);
      acc1 = MFMA16(a1, b, acc1);
    }
    float s[8], e[8];
    #pragma unroll
    for (int r = 0; r < 4; ++r) { s[r] = acc0[r] * 0.125f; s[4 + r] = acc1[r] * 0.125f; }
    float mx = s[0];
    #pragma unroll
    for (int i = 1; i < 8; ++i) mx = fmaxf(mx, s[i]);
    mx = fmaxf(mx, __shfl_xor(mx, 16));
    mx = fmaxf(mx, __shfl_xor(mx, 32));
    float sum = 0.f;
    #pragma unroll
    for (int i = 0; i < 8; ++i) { e[i] = __expf(s[i] - mx); sum += e[i]; }
    sum += __shfl_xor(sum, 16);
    sum += __shfl_xor(sum, 32);
    float inv = 1.f / sum;
    #pragma unroll
    for (int i = 0; i < 8; ++i) {
      int l = (i < 4) ? (qd * 4 + i) : (16 + qd * 4 + (i - 4));
      sATT[lm * 40 + l] = f2bf(e[i] * inv);
    }
  }
  __syncthreads();

  // mbar[h][d] = attn @ m  -> overwrite qkm[n] (bf16)
  {
    bf16x8 a = *(const bf16x8*)&sATT[lm * 40 + qd * 8];
    for (int dt = wid; dt < 20; dt += 4) {
      int d = dt * 16 + lm;
      bf16x8 b = *(const bf16x8*)&sMT[d * 40 + qd * 8];
      f32x4 acc = {};
      acc = MFMA16(a, b, acc);
      if (qd < 2) {
        #pragma unroll
        for (int r = 0; r < 4; ++r)
          qkm[(size_t)n * 2560 + (qd * 4 + r) * D_MODEL + d] = f2bf(acc[r]);
      }
    }
  }
}

// =================== K4: ctx -> fc(+q) -> LN -> out =========================
// grid 512 x 256 thr, G=16. LDS ~53 KB -> 3 blocks/CU.
__global__ __launch_bounds__(256, 3)
void tgat_post(const float* __restrict__ nf, const float* __restrict__ ph,
               const float* __restrict__ fcb, const float* __restrict__ lng,
               const float* __restrict__ lnb_, const float* __restrict__ nbias,
               const unsigned short* __restrict__ ws,
               const unsigned short* __restrict__ qkm, float* __restrict__ out)
{
  __shared__ alignas(16) unsigned short sCtx[16 * 520];  // 16.6 KB
  __shared__ alignas(16) float sX[16 * 321];             // 20.5 KB
  __shared__ alignas(16) unsigned short sXb[16 * 328];   // 10.5 KB
  __shared__ alignas(16) unsigned short sQb[16 * 136];   // 4.3 KB (h_dst bf16)
  __shared__ float cph[TIME_D];

  const int tid = threadIdx.x;
  const int wid = tid >> 6, lane = tid & 63, qd = lane >> 4, lm = lane & 15;
  const int n0 = blockIdx.x * 16;
  const unsigned short* wsWV  = ws + WS_WV;
  const unsigned short* wsFCW = ws + WS_FCW;
  const unsigned short* wsNW  = ws + WS_NW;

  if (tid < TIME_D) cph[tid] = __cosf(ph[tid]);
  { // stage h_dst bf16: thread -> (n = tid>>4, k8 = (tid&15)*8)
    int nn = tid >> 4, k0 = (tid & 15) * 8;
    const float4* src = (const float4*)(nf + (size_t)(n0 + nn) * NODE_IN + k0);
    float4 f0 = src[0], f1 = src[1];
    unsigned short b8[8] = { f2bf(f0.x), f2bf(f0.y), f2bf(f0.z), f2bf(f0.w),
                             f2bf(f1.x), f2bf(f1.y), f2bf(f1.z), f2bf(f1.w) };
    *(bf16x8*)&sQb[nn * 136 + k0] = *(const bf16x8*)b8;
  }

  // ctx: per head M=16(n), N=64, K=320; wave w -> heads {w, w+4}
  #pragma unroll
  for (int t = 0; t < 2; ++t) {
    const int h = wid + 4 * t;
    f32x4 acc[4] = {};
    for (int kt = 0; kt < 10; ++kt) {
      bf16x8 a = *(const bf16x8*)&qkm[(size_t)(n0 + lm) * 2560 + h * D_MODEL + kt * 32 + qd * 8];
      #pragma unroll
      for (int u = 0; u < 4; ++u) {
        int jv = h * 64 + u * 16 + lm;
        bf16x8 b = *(const bf16x8*)&wsWV[(size_t)jv * D_MODEL + kt * 32 + qd * 8];
        acc[u] = MFMA16(a, b, acc[u]);
      }
    }
    #pragma unroll
    for (int u = 0; u < 4; ++u)
      #pragma unroll
      for (int r = 0; r < 4; ++r)
        sCtx[(qd * 4 + r) * 520 + h * 64 + u * 16 + lm] = f2bf(acc[u][r]);
  }
  __syncthreads();

  // fc: M=16, N=320, K=512; wave w -> N-tiles {w+4u}, u<5; + fcb + q residual
  {
    f32x4 acc[5] = {};
    for (int ks = 0; ks < 16; ++ks) {
      bf16x8 a = *(const bf16x8*)&sCtx[lm * 520 + ks * 32 + qd * 8];
      #pragma unroll
      for (int u = 0; u < 5; ++u) {
        int c = (wid + 4 * u) * 16 + lm;
        bf16x8 b = *(const bf16x8*)&wsFCW[(size_t)c * NHD + ks * 32 + qd * 8];
        acc[u] = MFMA16(a, b, acc[u]);
      }
    }
    #pragma unroll
    for (int u = 0; u < 5; ++u) {
      int c = (wid + 4 * u) * 16 + lm;
      float fb = fcb[c];
      #pragma unroll
      for (int r = 0; r < 4; ++r) {
        int nn = qd * 4 + r;
        float qv;
        if (c < NODE_IN)      qv = nf[(size_t)(n0 + nn) * NODE_IN + c];
        else if (c < 192)     qv = 0.f;
        else                  qv = cph[c - 192];
        sX[nn * 321 + c] = acc[u][r] + fb + qv;
      }
    }
  }
  __syncthreads();

  // LN: wave w -> nodes 4w..4w+3
  #pragma unroll
  for (int t = 0; t < 4; ++t) {
    int nn = wid * 4 + t;
    float v[5], s = 0.f, s2 = 0.f;
    #pragma unroll
    for (int i = 0; i < 5; ++i) {
      v[i] = sX[nn * 321 + lane + 64 * i];
      s += v[i]; s2 += v[i] * v[i];
    }
    #pragma unroll
    for (int off = 32; off >= 1; off >>= 1) { s += __shfl_xor(s, off); s2 += __shfl_xor(s2, off); }
    float mean = s * (1.f / D_MODEL);
    float var  = s2 * (1.f / D_MODEL) - mean * mean;
    float rstd = rsqrtf(var + 1e-5f);
    #pragma unroll
    for (int i = 0; i < 5; ++i) {
      int c = lane + 64 * i;
      sXb[nn * 328 + c] = f2bf(lng[c] * ((v[i] - mean) * rstd) + lnb_[c]);
    }
  }
  __syncthreads();

  // out = relu([h_dst | h_neigh] @ nw^T + nb): M=16, N=128, K=448
  #pragma unroll
  for (int t = 0; t < 2; ++t) {
    int o = (wid + 4 * t) * 16 + lm;
    f32x4 acc = {};
    for (int ks = 0; ks < 14; ++ks) {
      bf16x8 a;
      if (ks < 4) a = *(const bf16x8*)&sQb[lm * 136 + ks * 32 + qd * 8];
      else        a = *(const bf16x8*)&sXb[lm * 328 + (ks - 4) * 32 + qd * 8];
      bf16x8 b = *(const bf16x8*)&wsNW[(size_t)o * IN2 + ks * 32 + qd * 8];
      acc = MFMA16(a, b, acc);
    }
    float nbv = nbias[o];
    #pragma unroll
    for (int r = 0; r < 4; ++r)
      out[(size_t)(n0 + qd * 4 + r) * HID + o] = fmaxf(acc[r] + nbv, 0.f);
  }
}

extern "C" void kernel_launch(void* const* d_in, const int* in_sizes, int n_in,
                              void* d_out, int out_size, void* d_ws, size_t ws_size,
                              hipStream_t stream) {
  const float* nf   = (const float*)d_in[0];
  const float* ef   = (const float*)d_in[1];
  const float* dtp  = (const float*)d_in[2];
  const int*   nidx = (const int*)  d_in[3];
  const float* freq = (const float*)d_in[4];
  const float* ph   = (const float*)d_in[5];
  const float* wq   = (const float*)d_in[6];
  const float* wk   = (const float*)d_in[7];
  const float* wv   = (const float*)d_in[8];
  const float* fcw  = (const float*)d_in[9];
  const float* fcb  = (const float*)d_in[10];
  const float* lng  = (const float*)d_in[11];
  const float* lnb_ = (const float*)d_in[12];
  const float* nw   = (const float*)d_in[13];
  const float* nb   = (const float*)d_in[14];
  float* out = (float*)d_out;
  unsigned short* ws = (unsigned short*)d_ws;
  unsigned short* qkm = ws + WS_QKM;

  prep_weights<<<640, 256, 0, stream>>>(wq, wk, wv, fcw, nw, ws);
  tgat_qk   <<<512,  256, 0, stream>>>(nf, ph, ws, qkm);
  tgat_attn <<<8192, 256, 0, stream>>>(nf, ef, dtp, nidx, freq, ph, qkm);
  tgat_post <<<512,  256, 0, stream>>>(nf, ph, fcb, lng, lnb_, nb, ws, qkm, out);
}